// Round 4
// baseline (1147.245 us; speedup 1.0000x reference)
//
#include <hip/hip_runtime.h>

#define TT 512   // max sequence length T
#define NN 128   // number of tags N
#define NTHR 512 // 4 compute waves + 4 extractor waves
#define SROW 160 // swizzled state row: 8 chunks x 20 floats (16 used + 4 pad)
#define SW(i) (20 * ((i) >> 4) + ((i) & 15))
#define BD  64   // backtrack chunk depth
#define MAXG 8   // max backtrack groups (TT/BD)

// Barrier WITHOUT vmcnt drain: LDS writes drained, global loads stay in flight.
#define STEP_BARRIER() asm volatile("s_waitcnt lgkmcnt(0)\n\ts_barrier" ::: "memory")

typedef float v2f __attribute__((ext_vector_type(2)));
__device__ __forceinline__ v2f vmax2(v2f a, v2f b) {
    v2f r; r.x = fmaxf(a.x, b.x); r.y = fmaxf(a.y, b.y); return r;
}

// DPP cross-lane (pure VALU, no LDS pipe)
template <int CTRL>
__device__ __forceinline__ int dpp_i(int x) {
    return __builtin_amdgcn_update_dpp(x, x, CTRL, 0xf, 0xf, true);
}
template <int CTRL>
__device__ __forceinline__ float dpp_f(float x) {
    union { float f; int i; } u; u.f = x;
    u.i = dpp_i<CTRL>(u.i);
    return u.f;
}
#define DPP_XOR1 0xB1   // quad_perm [1,0,3,2] : lane ^= 1
#define DPP_XOR2 0x4E   // quad_perm [2,3,0,1] : lane ^= 2

// R13: wave-specialized bp extraction.
// Waves 0-3 ("compute"): R3's max-only forward recursion, unchanged critical
// path; M[t] row goes to an 8-deep LDS ring (ws global store dropped).
// Waves 4-7 ("extract"): one step behind (same per-step barrier cadence, each
// side executes exactly lm1+1 barriers), recompute candidates
// (M[t-1][i]+x[t-1][i])+T[i][j] -- bitwise-identical to the forward's inputs
// (same adds, same operand bits) -- compare to M[t][j], ballot+ffs = exact
// first-occurrence argmax, pack bp bytes to LDS. Slack: extract issue
// (~400cy/step/wave) < forward step (~700cy), hides in compute stalls.
// Backtrack: proven parallel 8-group chase+stitch (~4us) replaces the ~90us
// serial ballot chase.
__global__ __launch_bounds__(NTHR, 1)
void crf_viterbi(const float* __restrict__ logits,
                 const float* __restrict__ trans,
                 const int* __restrict__ seqlen,
                 int* __restrict__ out) {
    __shared__ float stateBuf[2][SROW];
    __shared__ float mring[8][NN];                // M[t] ring, slot t&7
    __shared__ float redV[NN];
    __shared__ int   redI[NN];
    __shared__ int   tagBuf[TT];
    __shared__ int   entryTag[MAXG];
    __shared__ unsigned char bpArr[TT][NN];       // 64 KiB
    __shared__ unsigned char hist[MAXG][BD][NN];  // 64 KiB

    const int tid  = threadIdx.x;
    const int b    = blockIdx.x;
    const int L    = seqlen[b];   // in [1, TT]
    const int lm1  = L - 1;
    const int wave = tid >> 6;
    const float* lrow = logits + (size_t)b * TT * NN;

    if (wave < 4) {
        // ---------------- compute role (R3 forward, unchanged chain) -------
        const int j  = tid >> 2;   // 0..63 (serves tags j and j+64)
        const int c  = tid & 3;    // i-chunk (32 i's each)
        const int i0 = c << 5;
        const int jx = j + ((c & 1) << 6);

        auto xl = [&](int r) -> float {
            r = (r < lm1) ? r : lm1;
            return lrow[r * NN + jx];
        };
        float X0 = xl(1), X1 = xl(2), X2 = xl(3), X3 = xl(4);

        v2f tr0[16], tr1[16];
        #pragma unroll
        for (int p = 0; p < 16; ++p) {
            tr0[p].x = trans[(i0 + 2 * p)     * NN + j];
            tr0[p].y = trans[(i0 + 2 * p + 1) * NN + j];
            tr1[p].x = trans[(i0 + 2 * p)     * NN + j + 64];
            tr1[p].y = trans[(i0 + 2 * p + 1) * NN + j + 64];
        }
        if (c < 2) {
            stateBuf[0][SW(jx)] = lrow[jx];   // state(0) = x[0]
            mring[0][jx] = 0.0f;              // M[0] := 0
        }
        __syncthreads();

        #define REDUCE32(TR, OUT)                                              \
        {                                                                      \
            v2f m0 = vmax2(sv0 + TR[0],   sv1 + TR[1]);                        \
            v2f m1 = vmax2(sv2 + TR[2],   sv3 + TR[3]);                        \
            v2f m2 = vmax2(sv4 + TR[4],   sv5 + TR[5]);                        \
            v2f m3 = vmax2(sv6 + TR[6],   sv7 + TR[7]);                        \
            v2f m4 = vmax2(sv8 + TR[8],   sv9 + TR[9]);                        \
            v2f m5 = vmax2(sv10 + TR[10], sv11 + TR[11]);                      \
            v2f m6 = vmax2(sv12 + TR[12], sv13 + TR[13]);                      \
            v2f m7 = vmax2(sv14 + TR[14], sv15 + TR[15]);                      \
            m0 = vmax2(m0, m1); m2 = vmax2(m2, m3);                            \
            m4 = vmax2(m4, m5); m6 = vmax2(m6, m7);                            \
            m0 = vmax2(m0, m2); m4 = vmax2(m4, m6);                            \
            m0 = vmax2(m0, m4);                                                \
            OUT = fmaxf(m0.x, m0.y);                                           \
        }

        auto vstep = [&](const float* st, float* dst, int t, float& xslot) {
            float xa_use = xslot;          // x[t], loaded 4 steps ago
            int tn = t + 4;                // refill ring slot with x[t+4]
            tn = (tn < lm1) ? tn : lm1;
            xslot = lrow[tn * NN + jx];

            const float* sp = st + 40 * c;
            float4 a0 = *(const float4*)(sp);
            float4 a1 = *(const float4*)(sp + 4);
            float4 a2 = *(const float4*)(sp + 8);
            float4 a3 = *(const float4*)(sp + 12);
            float4 a4 = *(const float4*)(sp + 20);
            float4 a5 = *(const float4*)(sp + 24);
            float4 a6 = *(const float4*)(sp + 28);
            float4 a7 = *(const float4*)(sp + 32);

            v2f sv0  = {a0.x, a0.y}, sv1  = {a0.z, a0.w};
            v2f sv2  = {a1.x, a1.y}, sv3  = {a1.z, a1.w};
            v2f sv4  = {a2.x, a2.y}, sv5  = {a2.z, a2.w};
            v2f sv6  = {a3.x, a3.y}, sv7  = {a3.z, a3.w};
            v2f sv8  = {a4.x, a4.y}, sv9  = {a4.z, a4.w};
            v2f sv10 = {a5.x, a5.y}, sv11 = {a5.z, a5.w};
            v2f sv12 = {a6.x, a6.y}, sv13 = {a6.z, a6.w};
            v2f sv14 = {a7.x, a7.y}, sv15 = {a7.z, a7.w};

            float bv0, bv1;
            REDUCE32(tr0, bv0)
            REDUCE32(tr1, bv1)

            // value-only quad merge: all 4 lanes of the quad get both maxes
            bv0 = fmaxf(bv0, dpp_f<DPP_XOR1>(bv0)); bv1 = fmaxf(bv1, dpp_f<DPP_XOR1>(bv1));
            bv0 = fmaxf(bv0, dpp_f<DPP_XOR2>(bv0)); bv1 = fmaxf(bv1, dpp_f<DPP_XOR2>(bv1));

            // one LDS write per thread (balanced barrier arrival)
            if (c == 0)      dst[SW(j)]           = bv0 + xa_use;
            else if (c == 1) dst[SW(j + 64)]      = bv1 + xa_use;
            else if (c == 2) mring[t & 7][j]      = bv0;
            else             mring[t & 7][j + 64] = bv1;

            STEP_BARRIER();
        };
        #undef REDUCE32

        int t = 1;
        for (; t + 4 < L; t += 4) {
            vstep(stateBuf[0], stateBuf[1], t,     X0);
            vstep(stateBuf[1], stateBuf[0], t + 1, X1);
            vstep(stateBuf[0], stateBuf[1], t + 2, X2);
            vstep(stateBuf[1], stateBuf[0], t + 3, X3);
        }
        if (t     < L) vstep(stateBuf[0], stateBuf[1], t,     X0);
        if (t + 1 < L) vstep(stateBuf[1], stateBuf[0], t + 1, X1);
        if (t + 2 < L) vstep(stateBuf[0], stateBuf[1], t + 2, X2);
        if (t + 3 < L) vstep(stateBuf[1], stateBuf[0], t + 3, X3);
        STEP_BARRIER();   // pairs with extractor's final barrier
        // barriers executed: lm1 + 1
    } else {
        // ---------------- extract role: bp[t][j] one step behind -----------
        const int lane = tid & 63;
        const int wv   = wave - 4;    // 0..3
        const int jb   = wv << 5;     // this wave's 32-tag base
        const bool useHi = (wv >= 2); // tags 64..127 read the hi M half

        // T columns for this wave's tags: Te[s] = T[lane][jb+s], Te2 = T[lane+64][jb+s]
        float Te[32], Te2[32];
        #pragma unroll
        for (int q = 0; q < 8; ++q) {
            float4 v  = *(const float4*)&trans[lane * NN + jb + 4 * q];
            float4 v2 = *(const float4*)&trans[(lane + 64) * NN + jb + 4 * q];
            Te[4*q+0] = v.x;  Te[4*q+1] = v.y;  Te[4*q+2] = v.z;  Te[4*q+3] = v.w;
            Te2[4*q+0] = v2.x; Te2[4*q+1] = v2.y; Te2[4*q+2] = v2.z; Te2[4*q+3] = v2.w;
        }
        // x-row prefetch ring: slot i holds x[t-1] for its unroll position
        auto xe = [&](int r) -> float2 {
            r = (r < 0) ? 0 : ((r < lm1) ? r : lm1);
            return make_float2(lrow[r * NN + lane], lrow[r * NN + lane + 64]);
        };
        float2 E0 = xe(0), E1 = xe(1), E2 = xe(2), E3 = xe(3);
        __syncthreads();

        auto extract = [&](int t, float2 ex) {
            const int rt = t & 7, rp = (t - 1) & 7;
            // state(t-1)[i] = M[t-1][i] + x[t-1][i]  (bitwise == forward input)
            float slo = mring[rp][lane]      + ex.x;   // i = lane
            float shi = mring[rp][lane + 64] + ex.y;   // i = lane + 64
            float tsel = useHi ? mring[rt][lane + 64] : mring[rt][lane];
            unsigned word = 0;
            #pragma unroll
            for (int s = 0; s < 32; ++s) {
                float tgt = __int_as_float(
                    __builtin_amdgcn_readlane(__float_as_int(tsel), (jb + s) & 63));
                unsigned long long mA = __ballot(slo + Te[s]  == tgt);
                unsigned long long mB = __ballot(shi + Te2[s] == tgt);
                int bpi = mA ? (__ffsll((long long)mA) - 1)
                             : (mB ? (63 + __ffsll((long long)mB)) : 0);
                word |= (unsigned)bpi << (8 * (s & 3));
                if ((s & 3) == 3) {
                    if (lane == 0) *(unsigned*)&bpArr[t][jb + (s - 3)] = word;
                    word = 0;
                }
            }
        };

        int t = 1;
        for (; t + 3 <= lm1; t += 4) {
            STEP_BARRIER(); extract(t,     E0); E0 = xe(t + 3);
            STEP_BARRIER(); extract(t + 1, E1); E1 = xe(t + 4);
            STEP_BARRIER(); extract(t + 2, E2); E2 = xe(t + 5);
            STEP_BARRIER(); extract(t + 3, E3); E3 = xe(t + 6);
        }
        if (t <= lm1) { STEP_BARRIER(); extract(t, E0); ++t; }
        if (t <= lm1) { STEP_BARRIER(); extract(t, E1); ++t; }
        if (t <= lm1) { STEP_BARRIER(); extract(t, E2); ++t; }
        STEP_BARRIER();   // final
        // barriers executed: lm1 + 1  (matches compute role for every L)
    }
    __syncthreads();
    const int pf = (L - 1) & 1;

    // Final argmax over state (first-occurrence: min index on ties).
    if (tid < NN) { redV[tid] = stateBuf[pf][SW(tid)]; redI[tid] = tid; }
    __syncthreads();
    #pragma unroll
    for (int off = 64; off >= 1; off >>= 1) {
        if (tid < off) {
            float va = redV[tid], vb = redV[tid + off];
            int   ia = redI[tid], ib = redI[tid + off];
            if (vb > va || (vb == va && ib < ia)) { redV[tid] = vb; redI[tid] = ib; }
        }
        __syncthreads();
    }

    // ---- Parallel backtrack (proven): 8 groups x BD-deep chase of all 128
    // start tags through LDS bp, serial stitch over <=8 boundaries, expand.
    const int M = L - 1;
    const int G = (M + BD - 1) / BD;
    {
        int s  = tid & 127;
        int gA = tid >> 7;
        int gB = gA + 4;
        int thA = M - gA * BD, thB = M - gB * BD;
        int dA  = (gA < G) ? ((thA < BD) ? thA : BD) : 0;
        int dB  = (gB < G) ? ((thB < BD) ? thB : BD) : 0;
        int curA = s, curB = s;
        int maxd = (dA > dB) ? dA : dB;
        for (int d = 0; d < maxd; ++d) {
            if (d < dA) { curA = bpArr[thA - d][curA]; hist[gA][d][s] = (unsigned char)curA; }
            if (d < dB) { curB = bpArr[thB - d][curB]; hist[gB][d][s] = (unsigned char)curB; }
        }
    }
    __syncthreads();
    if (tid == 0) {
        int e = redI[0];
        tagBuf[L - 1] = e;
        for (int g = 0; g < G; ++g) {
            entryTag[g] = e;
            if (g + 1 < G) e = hist[g][BD - 1][e];
        }
    }
    __syncthreads();
    {
        int g = tid >> 6, d = tid & 63;
        if (g < MAXG && g < G) {
            int th  = M - g * BD;
            int dep = (th < BD) ? th : BD;
            if (d < dep) {
                int e = entryTag[g];
                tagBuf[th - 1 - d] = hist[g][d][e];
            }
        }
    }
    __syncthreads();

    // Coalesced output: tags for k < L, zeros for the masked tail.
    out[(size_t)b * TT + tid] = (tid < L) ? tagBuf[tid] : 0;
}

extern "C" void kernel_launch(void* const* d_in, const int* in_sizes, int n_in,
                              void* d_out, int out_size, void* d_ws, size_t ws_size,
                              hipStream_t stream) {
    const float* logits = (const float*)d_in[0];
    const float* trans  = (const float*)d_in[1];
    const int*   seqlen = (const int*)d_in[2];
    int*         out    = (int*)d_out;
    const int B = in_sizes[2];  // 256
    (void)d_ws; (void)ws_size;
    crf_viterbi<<<B, NTHR, 0, stream>>>(logits, trans, seqlen, out);
}

// Round 5
// 515.507 us; speedup vs baseline: 2.2255x; 2.2255x over previous
//
#include <hip/hip_runtime.h>

#define TT 512   // max sequence length T
#define NN 128   // number of tags N
#define NTHR 256 // 4 waves = 1 wave per SIMD
#define SROW 160 // swizzled state row: 8 chunks x 20 floats (16 used + 4 pad)
#define SW(i) (20 * ((i) >> 4) + ((i) & 15))
#define BD  64   // backtrack chunk depth
#define MAXG 8   // max backtrack groups (TT/BD)

// Barrier WITHOUT vmcnt drain: LDS writes drained, global loads stay in flight.
#define STEP_BARRIER() asm volatile("s_waitcnt lgkmcnt(0)\n\ts_barrier" ::: "memory")

typedef float v2f __attribute__((ext_vector_type(2)));
__device__ __forceinline__ v2f vmax2(v2f a, v2f b) {
    v2f r; r.x = fmaxf(a.x, b.x); r.y = fmaxf(a.y, b.y); return r;
}

// DPP cross-lane (pure VALU, no LDS pipe)
template <int CTRL>
__device__ __forceinline__ int dpp_i(int x) {
    return __builtin_amdgcn_update_dpp(x, x, CTRL, 0xf, 0xf, true);
}
template <int CTRL>
__device__ __forceinline__ float dpp_f(float x) {
    union { float f; int i; } u; u.f = x;
    u.i = dpp_i<CTRL>(u.i);
    return u.f;
}
#define DPP_XOR1 0xB1   // quad_perm [1,0,3,2] : lane ^= 1
#define DPP_XOR2 0x4E   // quad_perm [2,3,0,1] : lane ^= 2

// R14: delayed in-register bp extraction.
// R3 forward (unchanged critical chain, ~700cy/step vs ~260cy issue). At step
// t each thread keeps its 32 candidates cc[] and the merged max bvP (=M[t][j])
// in registers across the barrier. At step t+1, while the 8 ds_read_b128 state
// loads are in flight, a pure-VALU index-min scan (cmp+cndmask -> v_min3 tree
// -> 2 DPP quad-min stages; NO ballots/readlanes -- R13's fatal serial SALU
// ops) computes bp[t][j] = min{ i : cand_i == M[t][j] } = exact
// first-occurrence argmax (max is order-invariant-exact, candidates are the
// very registers the max came from). bp bytes -> LDS; proven parallel 8-group
// backtrack (+stitch, ~3us) replaces the ~90us serial ballot chase. ws/global
// M traffic eliminated.
__global__ __launch_bounds__(NTHR, 1)
void crf_viterbi(const float* __restrict__ logits,
                 const float* __restrict__ trans,
                 const int* __restrict__ seqlen,
                 int* __restrict__ out) {
    __shared__ float stateBuf[2][SROW];
    __shared__ float redV[NN];
    __shared__ int   redI[NN];
    __shared__ int   tagBuf[TT];
    __shared__ int   entryTag[MAXG];
    __shared__ unsigned char bpArr[TT][NN];       // 64 KiB
    __shared__ unsigned char hist[MAXG][BD][NN];  // 64 KiB

    const int tid = threadIdx.x;
    const int j   = tid >> 2;   // 0..63 (serves tags j and j+64)
    const int c   = tid & 3;    // i-chunk (32 i's each)
    const int i0  = c << 5;
    const int b   = blockIdx.x;
    const int L   = seqlen[b];  // in [1, TT]
    const int lm1 = L - 1;
    const int jx  = j + ((c & 1) << 6);

    const float* lrow = logits + (size_t)b * TT * NN;

    // 4-deep logits prefetch ring
    auto xl = [&](int r) -> float {
        r = (r < lm1) ? r : lm1;
        return lrow[r * NN + jx];
    };
    float X0 = xl(1), X1 = xl(2), X2 = xl(3), X3 = xl(4);

    // Transition chunks in registers, packed for v_pk_add_f32 / v_pk_max_f32
    v2f tr0[16], tr1[16];
    #pragma unroll
    for (int p = 0; p < 16; ++p) {
        tr0[p].x = trans[(i0 + 2 * p)     * NN + j];
        tr0[p].y = trans[(i0 + 2 * p + 1) * NN + j];
        tr1[p].x = trans[(i0 + 2 * p)     * NN + j + 64];
        tr1[p].y = trans[(i0 + 2 * p + 1) * NN + j + 64];
    }

    if (c < 2) stateBuf[0][SW(jx)] = lrow[jx];   // t = 0 init
    __syncthreads();

    // Persistent prev-step extraction context (regs). First extraction (pt=0)
    // writes bpArr[0], which the backtrack never reads (it stops at t=1).
    v2f  cc0[16], cc1[16];
    float bvP0 = 0.0f, bvP1 = 0.0f;
    #pragma unroll
    for (int k = 0; k < 16; ++k) { cc0[k] = (v2f){0, 0}; cc1[k] = (v2f){0, 0}; }

    // Pure-VALU first-occurrence argmax of the PREVIOUS step, written to LDS.
    // Independent cmp+cndmask pairs (compiler picks distinct sdst -> ILP), a
    // v_min3 chain, 2 DPP quad-min stages. No ballots, no readlanes.
    auto extract_prev = [&](int pt) {
        int s0 = 255, s1 = 255;
        #pragma unroll
        for (int k = 0; k < 16; ++k) {
            int ia = i0 + 2 * k, ib = i0 + 2 * k + 1;
            int e0a = (cc0[k].x == bvP0) ? ia : 255;
            int e0b = (cc0[k].y == bvP0) ? ib : 255;
            int e1a = (cc1[k].x == bvP1) ? ia : 255;
            int e1b = (cc1[k].y == bvP1) ? ib : 255;
            s0 = min(s0, min(e0a, e0b));   // v_min3-fusable
            s1 = min(s1, min(e1a, e1b));
        }
        s0 = min(s0, dpp_i<DPP_XOR1>(s0)); s1 = min(s1, dpp_i<DPP_XOR1>(s1));
        s0 = min(s0, dpp_i<DPP_XOR2>(s0)); s1 = min(s1, dpp_i<DPP_XOR2>(s1));
        if (c == 0)      bpArr[pt][j]      = (unsigned char)s0;
        else if (c == 1) bpArr[pt][j + 64] = (unsigned char)s1;
    };

    auto vstep = [&](const float* st, float* dst, int t, float& xslot) {
        float xa_use = xslot;          // x[t], loaded 4 steps ago
        int tn = t + 4;                // refill ring slot with x[t+4]
        tn = (tn < lm1) ? tn : lm1;
        xslot = lrow[tn * NN + jx];

        // issue state loads first (latency starts)...
        const float* sp = st + 40 * c;
        float4 a0 = *(const float4*)(sp);
        float4 a1 = *(const float4*)(sp + 4);
        float4 a2 = *(const float4*)(sp + 8);
        float4 a3 = *(const float4*)(sp + 12);
        float4 a4 = *(const float4*)(sp + 20);
        float4 a5 = *(const float4*)(sp + 24);
        float4 a6 = *(const float4*)(sp + 28);
        float4 a7 = *(const float4*)(sp + 32);

        // ...and fill the wait window with the prev step's bp extraction
        // (independent of everything above).
        extract_prev(t - 1);

        v2f sv0  = {a0.x, a0.y}, sv1  = {a0.z, a0.w};
        v2f sv2  = {a1.x, a1.y}, sv3  = {a1.z, a1.w};
        v2f sv4  = {a2.x, a2.y}, sv5  = {a2.z, a2.w};
        v2f sv6  = {a3.x, a3.y}, sv7  = {a3.z, a3.w};
        v2f sv8  = {a4.x, a4.y}, sv9  = {a4.z, a4.w};
        v2f sv10 = {a5.x, a5.y}, sv11 = {a5.z, a5.w};
        v2f sv12 = {a6.x, a6.y}, sv13 = {a6.z, a6.w};
        v2f sv14 = {a7.x, a7.y}, sv15 = {a7.z, a7.w};

        // candidates into the persistent regs (SSA-renamed; extraction above
        // consumed the old values)
        cc0[0]  = sv0  + tr0[0];   cc1[0]  = sv0  + tr1[0];
        cc0[1]  = sv1  + tr0[1];   cc1[1]  = sv1  + tr1[1];
        cc0[2]  = sv2  + tr0[2];   cc1[2]  = sv2  + tr1[2];
        cc0[3]  = sv3  + tr0[3];   cc1[3]  = sv3  + tr1[3];
        cc0[4]  = sv4  + tr0[4];   cc1[4]  = sv4  + tr1[4];
        cc0[5]  = sv5  + tr0[5];   cc1[5]  = sv5  + tr1[5];
        cc0[6]  = sv6  + tr0[6];   cc1[6]  = sv6  + tr1[6];
        cc0[7]  = sv7  + tr0[7];   cc1[7]  = sv7  + tr1[7];
        cc0[8]  = sv8  + tr0[8];   cc1[8]  = sv8  + tr1[8];
        cc0[9]  = sv9  + tr0[9];   cc1[9]  = sv9  + tr1[9];
        cc0[10] = sv10 + tr0[10];  cc1[10] = sv10 + tr1[10];
        cc0[11] = sv11 + tr0[11];  cc1[11] = sv11 + tr1[11];
        cc0[12] = sv12 + tr0[12];  cc1[12] = sv12 + tr1[12];
        cc0[13] = sv13 + tr0[13];  cc1[13] = sv13 + tr1[13];
        cc0[14] = sv14 + tr0[14];  cc1[14] = sv14 + tr1[14];
        cc0[15] = sv15 + tr0[15];  cc1[15] = sv15 + tr1[15];

        // value-only max trees (order-invariant -> exact)
        #define TREE(CC, OUT)                                                  \
        {                                                                      \
            v2f m0 = vmax2(CC[0], CC[1]);   v2f m1 = vmax2(CC[2], CC[3]);      \
            v2f m2 = vmax2(CC[4], CC[5]);   v2f m3 = vmax2(CC[6], CC[7]);      \
            v2f m4 = vmax2(CC[8], CC[9]);   v2f m5 = vmax2(CC[10], CC[11]);    \
            v2f m6 = vmax2(CC[12], CC[13]); v2f m7 = vmax2(CC[14], CC[15]);    \
            m0 = vmax2(m0, m1); m2 = vmax2(m2, m3);                            \
            m4 = vmax2(m4, m5); m6 = vmax2(m6, m7);                            \
            m0 = vmax2(m0, m2); m4 = vmax2(m4, m6);                            \
            m0 = vmax2(m0, m4);                                                \
            OUT = fmaxf(m0.x, m0.y);                                           \
        }
        float bv0, bv1;
        TREE(cc0, bv0)
        TREE(cc1, bv1)
        #undef TREE

        // value-only quad merge: all 4 quad lanes get both full maxes
        bv0 = fmaxf(bv0, dpp_f<DPP_XOR1>(bv0)); bv1 = fmaxf(bv1, dpp_f<DPP_XOR1>(bv1));
        bv0 = fmaxf(bv0, dpp_f<DPP_XOR2>(bv0)); bv1 = fmaxf(bv1, dpp_f<DPP_XOR2>(bv1));

        if (c < 2) {
            float bv = c ? bv1 : bv0;
            dst[SW(jx)] = bv + xa_use;   // next step's state S[t]
        }
        bvP0 = bv0; bvP1 = bv1;          // extraction context for step t+1
        STEP_BARRIER();   // lgkm-only: global loads stay in flight
    };

    int t = 1;
    for (; t + 4 < L; t += 4) {
        vstep(stateBuf[0], stateBuf[1], t,     X0);
        vstep(stateBuf[1], stateBuf[0], t + 1, X1);
        vstep(stateBuf[0], stateBuf[1], t + 2, X2);
        vstep(stateBuf[1], stateBuf[0], t + 3, X3);
    }
    if (t     < L) vstep(stateBuf[0], stateBuf[1], t,     X0);
    if (t + 1 < L) vstep(stateBuf[1], stateBuf[0], t + 1, X1);
    if (t + 2 < L) vstep(stateBuf[0], stateBuf[1], t + 2, X2);
    if (t + 3 < L) vstep(stateBuf[1], stateBuf[0], t + 3, X3);

    extract_prev(lm1);   // bp for the final step (L==1: writes unread bp[0])
    __syncthreads();
    const int pf = (L - 1) & 1;

    // Final argmax over state (first-occurrence: min index on ties).
    if (tid < NN) { redV[tid] = stateBuf[pf][SW(tid)]; redI[tid] = tid; }
    __syncthreads();
    #pragma unroll
    for (int off = 64; off >= 1; off >>= 1) {
        if (tid < off) {
            float va = redV[tid], vb = redV[tid + off];
            int   ia = redI[tid], ib = redI[tid + off];
            if (vb > va || (vb == va && ib < ia)) { redV[tid] = vb; redI[tid] = ib; }
        }
        __syncthreads();
    }

    // ---- Parallel backtrack (proven structure, 256-thread variant): each
    // thread chases 4 of the 8 groups (interleaved chains -> ILP), then
    // serial stitch over <=8 boundaries, then 2-pass parallel expand.
    const int M = L - 1;
    const int G = (M + BD - 1) / BD;
    {
        int s = tid & 127;
        int h = tid >> 7;                 // 0..1
        int g0 = h, g1 = h + 2, g2 = h + 4, g3 = h + 6;
        int th0 = M - g0 * BD, th1 = M - g1 * BD;
        int th2 = M - g2 * BD, th3 = M - g3 * BD;
        int d0 = (g0 < G) ? ((th0 < BD) ? th0 : BD) : 0;
        int d1 = (g1 < G) ? ((th1 < BD) ? th1 : BD) : 0;
        int d2 = (g2 < G) ? ((th2 < BD) ? th2 : BD) : 0;
        int d3 = (g3 < G) ? ((th3 < BD) ? th3 : BD) : 0;
        int cur0 = s, cur1 = s, cur2 = s, cur3 = s;
        int maxd = max(max(d0, d1), max(d2, d3));
        for (int d = 0; d < maxd; ++d) {
            if (d < d0) { cur0 = bpArr[th0 - d][cur0]; hist[g0][d][s] = (unsigned char)cur0; }
            if (d < d1) { cur1 = bpArr[th1 - d][cur1]; hist[g1][d][s] = (unsigned char)cur1; }
            if (d < d2) { cur2 = bpArr[th2 - d][cur2]; hist[g2][d][s] = (unsigned char)cur2; }
            if (d < d3) { cur3 = bpArr[th3 - d][cur3]; hist[g3][d][s] = (unsigned char)cur3; }
        }
    }
    __syncthreads();
    if (tid == 0) {
        int e = redI[0];
        tagBuf[L - 1] = e;
        for (int g = 0; g < G; ++g) {
            entryTag[g] = e;
            if (g + 1 < G) e = hist[g][BD - 1][e];
        }
    }
    __syncthreads();
    {
        int d = tid & 63;
        #pragma unroll
        for (int pass = 0; pass < 2; ++pass) {
            int g = (tid >> 6) + 4 * pass;   // 0..3, then 4..7
            if (g < G) {
                int th  = M - g * BD;
                int dep = (th < BD) ? th : BD;
                if (d < dep) {
                    int e = entryTag[g];
                    tagBuf[th - 1 - d] = hist[g][d][e];
                }
            }
        }
    }
    __syncthreads();

    // Coalesced output: tags for k < L, zeros for the masked tail.
    out[(size_t)b * TT + tid]       = (tid < L)       ? tagBuf[tid]       : 0;
    out[(size_t)b * TT + tid + 256] = (tid + 256 < L) ? tagBuf[tid + 256] : 0;
}

extern "C" void kernel_launch(void* const* d_in, const int* in_sizes, int n_in,
                              void* d_out, int out_size, void* d_ws, size_t ws_size,
                              hipStream_t stream) {
    const float* logits = (const float*)d_in[0];
    const float* trans  = (const float*)d_in[1];
    const int*   seqlen = (const int*)d_in[2];
    int*         out    = (int*)d_out;
    const int B = in_sizes[2];  // 256
    (void)d_ws; (void)ws_size;
    crf_viterbi<<<B, NTHR, 0, stream>>>(logits, trans, seqlen, out);
}

// Round 6
// 457.451 us; speedup vs baseline: 2.5079x; 1.1269x over previous
//
#include <hip/hip_runtime.h>

#define TT 512   // max sequence length T
#define NN 128   // number of tags N
#define NTHR 256 // 4 waves = 1 wave per SIMD
#define SROW 160 // swizzled state row: 8 chunks x 20 floats (16 used + 4 pad)
#define SW(i) (20 * ((i) >> 4) + ((i) & 15))
#define BD  64   // backtrack chunk depth
#define MAXG 8   // max backtrack groups (TT/BD)

// Barrier WITHOUT vmcnt drain: LDS writes drained, global loads stay in flight.
#define STEP_BARRIER() asm volatile("s_waitcnt lgkmcnt(0)\n\ts_barrier" ::: "memory")

typedef float v2f __attribute__((ext_vector_type(2)));
__device__ __forceinline__ v2f vmax2(v2f a, v2f b) {
    v2f r; r.x = fmaxf(a.x, b.x); r.y = fmaxf(a.y, b.y); return r;
}

// DPP cross-lane (pure VALU, no LDS pipe)
template <int CTRL>
__device__ __forceinline__ int dpp_i(int x) {
    return __builtin_amdgcn_update_dpp(x, x, CTRL, 0xf, 0xf, true);
}
template <int CTRL>
__device__ __forceinline__ float dpp_f(float x) {
    union { float f; int i; } u; u.f = x;
    u.i = dpp_i<CTRL>(u.i);
    return u.f;
}
#define DPP_XOR1 0xB1   // quad_perm [1,0,3,2] : lane ^= 1
#define DPP_XOR2 0x4E   // quad_perm [2,3,0,1] : lane ^= 2

// R15: VCC-free delayed bp extraction.
// R14 post-mortem: per-candidate (x==bv)?i:255 compiles to v_cmp/v_cndmask
// through VCC -> 128 serialized ~10cy hazards = +1400cy/step. Same root cause
// killed R2 and R4 (ballots). Fix: zero comparison instructions.
//   d = bv - cand  (exact: bv is the fmax of these very registers; d==+0 iff
//   cand==bv, else positive NORMAL float -> bits >= 0x00800000)
//   key = v_min_u32(bits(d), 256) + i   (match -> i < 128; else >= 256)
//   v_min3_u32 tree + 2 DPP quad-min stages -> exact first-occurrence argmax.
// All plain VALU, no VCC/SALU, pipelines into the ds_read shadow one step
// delayed (R14 skeleton, which passed absmax 0 -- only the extraction
// arithmetic changes). Serial ballot chase, ws and tt are gone; proven
// parallel 8-group backtrack (~3us) recovers the path.
__global__ __launch_bounds__(NTHR, 1)
void crf_viterbi(const float* __restrict__ logits,
                 const float* __restrict__ trans,
                 const int* __restrict__ seqlen,
                 int* __restrict__ out) {
    __shared__ float stateBuf[2][SROW];
    __shared__ float redV[NN];
    __shared__ int   redI[NN];
    __shared__ int   tagBuf[TT];
    __shared__ int   entryTag[MAXG];
    __shared__ unsigned char bpArr[TT][NN];       // 64 KiB
    __shared__ unsigned char hist[MAXG][BD][NN];  // 64 KiB

    const int tid = threadIdx.x;
    const int j   = tid >> 2;   // 0..63 (serves tags j and j+64)
    const int c   = tid & 3;    // i-chunk (32 i's each)
    const int i0  = c << 5;
    const int b   = blockIdx.x;
    const int L   = seqlen[b];  // in [1, TT]
    const int lm1 = L - 1;
    const int jx  = j + ((c & 1) << 6);

    const float* lrow = logits + (size_t)b * TT * NN;

    // 4-deep logits prefetch ring
    auto xl = [&](int r) -> float {
        r = (r < lm1) ? r : lm1;
        return lrow[r * NN + jx];
    };
    float X0 = xl(1), X1 = xl(2), X2 = xl(3), X3 = xl(4);

    // Transition chunks in registers, packed for v_pk_add_f32 / v_pk_max_f32
    v2f tr0[16], tr1[16];
    #pragma unroll
    for (int p = 0; p < 16; ++p) {
        tr0[p].x = trans[(i0 + 2 * p)     * NN + j];
        tr0[p].y = trans[(i0 + 2 * p + 1) * NN + j];
        tr1[p].x = trans[(i0 + 2 * p)     * NN + j + 64];
        tr1[p].y = trans[(i0 + 2 * p + 1) * NN + j + 64];
    }

    if (c < 2) stateBuf[0][SW(jx)] = lrow[jx];   // t = 0 init
    __syncthreads();

    // Persistent prev-step extraction context (regs). First extraction (pt=0)
    // writes bpArr[0], which the backtrack never reads (it stops at t=1).
    v2f  cc0[16], cc1[16];
    float bvP0 = 0.0f, bvP1 = 0.0f;
    #pragma unroll
    for (int k = 0; k < 16; ++k) { cc0[k] = (v2f){0, 0}; cc1[k] = (v2f){0, 0}; }

    // VCC-free first-occurrence argmax of the PREVIOUS step -> LDS bp.
    // pk_sub + v_min_u32 + v_add + v_min3 tree + 2 DPP stages. No v_cmp.
    auto extract_prev = [&](int pt) {
        v2f bq0 = {bvP0, bvP0}, bq1 = {bvP1, bvP1};
        int sA0 = 1 << 30, sB0 = 1 << 30, sA1 = 1 << 30, sB1 = 1 << 30;
        #pragma unroll
        for (int k = 0; k < 16; ++k) {
            v2f d0 = bq0 - cc0[k];   // v_pk_add_f32 neg; >= +0 exactly
            v2f d1 = bq1 - cc1[k];
            unsigned f0a = min(__float_as_uint(d0.x), 256u);
            unsigned f0b = min(__float_as_uint(d0.y), 256u);
            unsigned f1a = min(__float_as_uint(d1.x), 256u);
            unsigned f1b = min(__float_as_uint(d1.y), 256u);
            int k0a = (int)f0a + (i0 + 2 * k);
            int k0b = (int)f0b + (i0 + 2 * k + 1);
            int k1a = (int)f1a + (i0 + 2 * k);
            int k1b = (int)f1b + (i0 + 2 * k + 1);
            if (k & 1) { sB0 = min(sB0, min(k0a, k0b)); sB1 = min(sB1, min(k1a, k1b)); }
            else       { sA0 = min(sA0, min(k0a, k0b)); sA1 = min(sA1, min(k1a, k1b)); }
        }
        int s0 = min(sA0, sB0), s1 = min(sA1, sB1);
        s0 = min(s0, dpp_i<DPP_XOR1>(s0)); s1 = min(s1, dpp_i<DPP_XOR1>(s1));
        s0 = min(s0, dpp_i<DPP_XOR2>(s0)); s1 = min(s1, dpp_i<DPP_XOR2>(s1));
        if (c == 0)      bpArr[pt][j]      = (unsigned char)s0;
        else if (c == 1) bpArr[pt][j + 64] = (unsigned char)s1;
    };

    auto vstep = [&](const float* st, float* dst, int t, float& xslot) {
        float xa_use = xslot;          // x[t], loaded 4 steps ago
        int tn = t + 4;                // refill ring slot with x[t+4]
        tn = (tn < lm1) ? tn : lm1;
        xslot = lrow[tn * NN + jx];

        // issue state loads first (latency starts)...
        const float* sp = st + 40 * c;
        float4 a0 = *(const float4*)(sp);
        float4 a1 = *(const float4*)(sp + 4);
        float4 a2 = *(const float4*)(sp + 8);
        float4 a3 = *(const float4*)(sp + 12);
        float4 a4 = *(const float4*)(sp + 20);
        float4 a5 = *(const float4*)(sp + 24);
        float4 a6 = *(const float4*)(sp + 28);
        float4 a7 = *(const float4*)(sp + 32);

        // ...and fill the wait window with the prev step's bp extraction
        // (independent of everything above, pure VALU).
        extract_prev(t - 1);

        v2f sv0  = {a0.x, a0.y}, sv1  = {a0.z, a0.w};
        v2f sv2  = {a1.x, a1.y}, sv3  = {a1.z, a1.w};
        v2f sv4  = {a2.x, a2.y}, sv5  = {a2.z, a2.w};
        v2f sv6  = {a3.x, a3.y}, sv7  = {a3.z, a3.w};
        v2f sv8  = {a4.x, a4.y}, sv9  = {a4.z, a4.w};
        v2f sv10 = {a5.x, a5.y}, sv11 = {a5.z, a5.w};
        v2f sv12 = {a6.x, a6.y}, sv13 = {a6.z, a6.w};
        v2f sv14 = {a7.x, a7.y}, sv15 = {a7.z, a7.w};

        // candidates into the persistent regs (SSA-renamed; extraction above
        // consumed the old values)
        cc0[0]  = sv0  + tr0[0];   cc1[0]  = sv0  + tr1[0];
        cc0[1]  = sv1  + tr0[1];   cc1[1]  = sv1  + tr1[1];
        cc0[2]  = sv2  + tr0[2];   cc1[2]  = sv2  + tr1[2];
        cc0[3]  = sv3  + tr0[3];   cc1[3]  = sv3  + tr1[3];
        cc0[4]  = sv4  + tr0[4];   cc1[4]  = sv4  + tr1[4];
        cc0[5]  = sv5  + tr0[5];   cc1[5]  = sv5  + tr1[5];
        cc0[6]  = sv6  + tr0[6];   cc1[6]  = sv6  + tr1[6];
        cc0[7]  = sv7  + tr0[7];   cc1[7]  = sv7  + tr1[7];
        cc0[8]  = sv8  + tr0[8];   cc1[8]  = sv8  + tr1[8];
        cc0[9]  = sv9  + tr0[9];   cc1[9]  = sv9  + tr1[9];
        cc0[10] = sv10 + tr0[10];  cc1[10] = sv10 + tr1[10];
        cc0[11] = sv11 + tr0[11];  cc1[11] = sv11 + tr1[11];
        cc0[12] = sv12 + tr0[12];  cc1[12] = sv12 + tr1[12];
        cc0[13] = sv13 + tr0[13];  cc1[13] = sv13 + tr1[13];
        cc0[14] = sv14 + tr0[14];  cc1[14] = sv14 + tr1[14];
        cc0[15] = sv15 + tr0[15];  cc1[15] = sv15 + tr1[15];

        // value-only max trees (order-invariant -> exact)
        #define TREE(CC, OUT)                                                  \
        {                                                                      \
            v2f m0 = vmax2(CC[0], CC[1]);   v2f m1 = vmax2(CC[2], CC[3]);      \
            v2f m2 = vmax2(CC[4], CC[5]);   v2f m3 = vmax2(CC[6], CC[7]);      \
            v2f m4 = vmax2(CC[8], CC[9]);   v2f m5 = vmax2(CC[10], CC[11]);    \
            v2f m6 = vmax2(CC[12], CC[13]); v2f m7 = vmax2(CC[14], CC[15]);    \
            m0 = vmax2(m0, m1); m2 = vmax2(m2, m3);                            \
            m4 = vmax2(m4, m5); m6 = vmax2(m6, m7);                            \
            m0 = vmax2(m0, m2); m4 = vmax2(m4, m6);                            \
            m0 = vmax2(m0, m4);                                                \
            OUT = fmaxf(m0.x, m0.y);                                           \
        }
        float bv0, bv1;
        TREE(cc0, bv0)
        TREE(cc1, bv1)
        #undef TREE

        // value-only quad merge: all 4 quad lanes get both full maxes
        bv0 = fmaxf(bv0, dpp_f<DPP_XOR1>(bv0)); bv1 = fmaxf(bv1, dpp_f<DPP_XOR1>(bv1));
        bv0 = fmaxf(bv0, dpp_f<DPP_XOR2>(bv0)); bv1 = fmaxf(bv1, dpp_f<DPP_XOR2>(bv1));

        if (c < 2) {
            float bv = c ? bv1 : bv0;
            dst[SW(jx)] = bv + xa_use;   // next step's state S[t]
        }
        bvP0 = bv0; bvP1 = bv1;          // extraction context for step t+1
        STEP_BARRIER();   // lgkm-only: global loads stay in flight
    };

    int t = 1;
    for (; t + 4 < L; t += 4) {
        vstep(stateBuf[0], stateBuf[1], t,     X0);
        vstep(stateBuf[1], stateBuf[0], t + 1, X1);
        vstep(stateBuf[0], stateBuf[1], t + 2, X2);
        vstep(stateBuf[1], stateBuf[0], t + 3, X3);
    }
    if (t     < L) vstep(stateBuf[0], stateBuf[1], t,     X0);
    if (t + 1 < L) vstep(stateBuf[1], stateBuf[0], t + 1, X1);
    if (t + 2 < L) vstep(stateBuf[0], stateBuf[1], t + 2, X2);
    if (t + 3 < L) vstep(stateBuf[1], stateBuf[0], t + 3, X3);

    extract_prev(lm1);   // bp for the final step (L==1: writes unread bp[0])
    __syncthreads();
    const int pf = (L - 1) & 1;

    // Final argmax over state (first-occurrence: min index on ties).
    if (tid < NN) { redV[tid] = stateBuf[pf][SW(tid)]; redI[tid] = tid; }
    __syncthreads();
    #pragma unroll
    for (int off = 64; off >= 1; off >>= 1) {
        if (tid < off) {
            float va = redV[tid], vb = redV[tid + off];
            int   ia = redI[tid], ib = redI[tid + off];
            if (vb > va || (vb == va && ib < ia)) { redV[tid] = vb; redI[tid] = ib; }
        }
        __syncthreads();
    }

    // ---- Parallel backtrack (proven in R14): each thread chases 4 of the 8
    // groups (interleaved chains -> ILP), serial stitch over <=8 boundaries,
    // 2-pass parallel expand.
    const int M = L - 1;
    const int G = (M + BD - 1) / BD;
    {
        int s = tid & 127;
        int h = tid >> 7;                 // 0..1
        int g0 = h, g1 = h + 2, g2 = h + 4, g3 = h + 6;
        int th0 = M - g0 * BD, th1 = M - g1 * BD;
        int th2 = M - g2 * BD, th3 = M - g3 * BD;
        int d0 = (g0 < G) ? ((th0 < BD) ? th0 : BD) : 0;
        int d1 = (g1 < G) ? ((th1 < BD) ? th1 : BD) : 0;
        int d2 = (g2 < G) ? ((th2 < BD) ? th2 : BD) : 0;
        int d3 = (g3 < G) ? ((th3 < BD) ? th3 : BD) : 0;
        int cur0 = s, cur1 = s, cur2 = s, cur3 = s;
        int maxd = max(max(d0, d1), max(d2, d3));
        for (int d = 0; d < maxd; ++d) {
            if (d < d0) { cur0 = bpArr[th0 - d][cur0]; hist[g0][d][s] = (unsigned char)cur0; }
            if (d < d1) { cur1 = bpArr[th1 - d][cur1]; hist[g1][d][s] = (unsigned char)cur1; }
            if (d < d2) { cur2 = bpArr[th2 - d][cur2]; hist[g2][d][s] = (unsigned char)cur2; }
            if (d < d3) { cur3 = bpArr[th3 - d][cur3]; hist[g3][d][s] = (unsigned char)cur3; }
        }
    }
    __syncthreads();
    if (tid == 0) {
        int e = redI[0];
        tagBuf[L - 1] = e;
        for (int g = 0; g < G; ++g) {
            entryTag[g] = e;
            if (g + 1 < G) e = hist[g][BD - 1][e];
        }
    }
    __syncthreads();
    {
        int d = tid & 63;
        #pragma unroll
        for (int pass = 0; pass < 2; ++pass) {
            int g = (tid >> 6) + 4 * pass;   // 0..3, then 4..7
            if (g < G) {
                int th  = M - g * BD;
                int dep = (th < BD) ? th : BD;
                if (d < dep) {
                    int e = entryTag[g];
                    tagBuf[th - 1 - d] = hist[g][d][e];
                }
            }
        }
    }
    __syncthreads();

    // Coalesced output: tags for k < L, zeros for the masked tail.
    out[(size_t)b * TT + tid]       = (tid < L)       ? tagBuf[tid]       : 0;
    out[(size_t)b * TT + tid + 256] = (tid + 256 < L) ? tagBuf[tid + 256] : 0;
}

extern "C" void kernel_launch(void* const* d_in, const int* in_sizes, int n_in,
                              void* d_out, int out_size, void* d_ws, size_t ws_size,
                              hipStream_t stream) {
    const float* logits = (const float*)d_in[0];
    const float* trans  = (const float*)d_in[1];
    const int*   seqlen = (const int*)d_in[2];
    int*         out    = (int*)d_out;
    const int B = in_sizes[2];  // 256
    (void)d_ws; (void)ws_size;
    crf_viterbi<<<B, NTHR, 0, stream>>>(logits, trans, seqlen, out);
}

// Round 7
// 403.659 us; speedup vs baseline: 2.8421x; 1.1333x over previous
//
#include <hip/hip_runtime.h>

#define TT 512   // max sequence length T
#define NN 128   // number of tags N
#define NTHR 256 // FAST kernel: 4 waves
#define FTHR 512 // fallback kernel thread count
#define SROW 192 // state row: 16 chunks x 12 floats (8 used + 4 pad), 16B-aligned
#define SW(i) (12 * ((i) >> 3) + ((i) & 7))
#define FSROW 160 // fallback layout
#define SWF(i) (20 * ((i) >> 4) + ((i) & 15))
#define TTS 130  // tt (T^T) row stride in floats: bank step 2, float2-aligned
#define BD  64   // (fallback) backtrack chunk depth
#define MAXG 8   // (fallback)

// Barrier WITHOUT vmcnt drain: LDS writes drained, global loads/stores stay
// in flight across the barrier.
#define STEP_BARRIER() asm volatile("s_waitcnt lgkmcnt(0)\n\ts_barrier" ::: "memory")

typedef float v2f __attribute__((ext_vector_type(2)));
__device__ __forceinline__ v2f vmax2(v2f a, v2f b) {
    v2f r; r.x = fmaxf(a.x, b.x); r.y = fmaxf(a.y, b.y); return r;
}

// DPP cross-lane (pure VALU, no LDS pipe)
template <int CTRL>
__device__ __forceinline__ int dpp_i(int x) {
    return __builtin_amdgcn_update_dpp(x, x, CTRL, 0xf, 0xf, true);
}
template <int CTRL>
__device__ __forceinline__ float dpp_f(float x) {
    union { float f; int i; } u; u.f = x;
    u.i = dpp_i<CTRL>(u.i);
    return u.f;
}
#define DPP_XOR1  0xB1   // quad_perm [1,0,3,2] : lane ^= 1
#define DPP_XOR2  0x4E   // quad_perm [2,3,0,1] : lane ^= 2
#define DPP_MIR7  0x141  // row_half_mirror: lane ^= 7 (== ^4 after ^1,^2)
#define DPP_MIR15 0x140  // row_mirror:      lane ^= 15 (== ^8 after ^1,^2,^7)

// R16: DS-pipe-thin forward. R3's step was dominated by LDS pipe occupancy
// (4 waves x 8 ds_read_b128 x ~12cy = ~384cy/step serialized on the one DS
// pipe per CU). Re-tile: lane (g=lane>>4, c=lane&15) covers 8 tags
// (jb=wave*32+g*8) x 8 states (i in [8c,8c+8)) -> 2 ds_read_b128/lane
// (~96cy DS/step, 4x cut). Tag merge = 16-lane row reduce via 4 DPP stages
// (^1,^2,mir7,mir15; value-only max -> order-invariant-exact). Chase / ws /
// tt byte-for-byte R3 (proven absmax 0).
__global__ __launch_bounds__(NTHR, 1)
void crf_viterbi_fast(const float* __restrict__ logits,
                      const float* __restrict__ trans,
                      const int* __restrict__ seqlen,
                      int* __restrict__ out,
                      float* __restrict__ ws) {
    __shared__ float stateBuf[2][SROW];
    __shared__ float tt[NN * TTS];  // tt[j*TTS+i] = trans[i*NN+j]
    __shared__ float redV[NN];
    __shared__ int   redI[NN];
    __shared__ int   tagBuf[TT];

    const int tid  = threadIdx.x;
    const int wave = tid >> 6;
    const int lane = tid & 63;
    const int g    = lane >> 4;     // tag-group within wave
    const int c    = lane & 15;     // i-chunk (8 states)
    const int jb   = wave * 32 + g * 8;   // this thread's 8 tags: jb..jb+7
    const int b    = blockIdx.x;
    const int L    = seqlen[b];     // in [1, TT]
    const int lm1  = L - 1;

    const float* lrow = logits + (size_t)b * TT * NN;
    float* wsb = ws + (size_t)b * TT * NN;

    // x prefetch ring: 8 floats (this thread's 8 tags) per slot. Address is
    // uniform across the 16 lanes of a row -> HW coalesces to one fetch.
    struct X8 { float4 a, b; };
    auto xl = [&](int r) -> X8 {
        r = (r < lm1) ? r : lm1;
        X8 v;
        v.a = *(const float4*)(lrow + r * NN + jb);
        v.b = *(const float4*)(lrow + r * NN + jb + 4);
        return v;
    };
    X8 X0 = xl(1), X1 = xl(2), X2 = xl(3), X3 = xl(4);

    // Transition block in registers: tr[u][q] = {T[8c+2q][jb+u], T[8c+2q+1][jb+u]}
    v2f tr[8][4];
    #pragma unroll
    for (int u = 0; u < 8; ++u)
        #pragma unroll
        for (int q = 0; q < 4; ++q) {
            tr[u][q].x = trans[(8 * c + 2 * q)     * NN + jb + u];
            tr[u][q].y = trans[(8 * c + 2 * q + 1) * NN + jb + u];
        }

    // Transposed copy for the backtrack chase (unchanged from R3).
    for (int k = 0; k < (NN * NN) / NTHR; ++k) {
        int idx = k * NTHR + tid;
        tt[(idx & 127) * TTS + (idx >> 7)] = trans[idx];
    }

    if (tid < NN) {   // t = 0 init: state = x[0]; ws row 0 = 0 (M[0] := 0)
        stateBuf[0][SW(tid)] = lrow[tid];
        wsb[tid] = 0.0f;
    }
    __syncthreads();

    auto vstep = [&](const float* st, float* dst, int t, X8& xslot) {
        X8 xa = xslot;                 // x[t] rows jb..jb+8, loaded 4 steps ago
        int tn = t + 4;                // refill ring slot with x[t+4]
        tn = (tn < lm1) ? tn : lm1;
        xslot.a = *(const float4*)(lrow + tn * NN + jb);
        xslot.b = *(const float4*)(lrow + tn * NN + jb + 4);

        // 8 states of chunk c (2 x b128, 16B-aligned, 2-way bank alias = free)
        const float* sp = st + 12 * c;
        float4 a0 = *(const float4*)(sp);
        float4 a1 = *(const float4*)(sp + 4);
        v2f sv0 = {a0.x, a0.y}, sv1 = {a0.z, a0.w};
        v2f sv2 = {a1.x, a1.y}, sv3 = {a1.z, a1.w};

        // per-tag local max over this chunk's 8 states
        float bv[8];
        #pragma unroll
        for (int u = 0; u < 8; ++u) {
            v2f c0 = sv0 + tr[u][0];
            v2f c1 = sv1 + tr[u][1];
            v2f c2 = sv2 + tr[u][2];
            v2f c3 = sv3 + tr[u][3];
            v2f m  = vmax2(vmax2(c0, c1), vmax2(c2, c3));
            bv[u]  = fmaxf(m.x, m.y);
        }

        // 16-lane row merge across chunks (value-only, order-invariant)
        #pragma unroll
        for (int u = 0; u < 8; ++u) bv[u] = fmaxf(bv[u], dpp_f<DPP_XOR1>(bv[u]));
        #pragma unroll
        for (int u = 0; u < 8; ++u) bv[u] = fmaxf(bv[u], dpp_f<DPP_XOR2>(bv[u]));
        #pragma unroll
        for (int u = 0; u < 8; ++u) bv[u] = fmaxf(bv[u], dpp_f<DPP_MIR7>(bv[u]));
        #pragma unroll
        for (int u = 0; u < 8; ++u) bv[u] = fmaxf(bv[u], dpp_f<DPP_MIR15>(bv[u]));

        if (c == 0) {   // 4 lanes/wave write: state chunk jb>>3 + ws row slice
            float4 w0 = {bv[0] + xa.a.x, bv[1] + xa.a.y,
                         bv[2] + xa.a.z, bv[3] + xa.a.w};
            float4 w1 = {bv[4] + xa.b.x, bv[5] + xa.b.y,
                         bv[6] + xa.b.z, bv[7] + xa.b.w};
            float* dp = dst + SW(jb);
            *(float4*)(dp)     = w0;   // next step's state S[t]
            *(float4*)(dp + 4) = w1;
            float4 m0 = {bv[0], bv[1], bv[2], bv[3]};
            float4 m1 = {bv[4], bv[5], bv[6], bv[7]};
            *(float4*)(wsb + t * NN + jb)     = m0;   // pre-logit max M[t]
            *(float4*)(wsb + t * NN + jb + 4) = m1;
        }
        STEP_BARRIER();   // lgkm-only: global loads/stores stay in flight
    };

    int t = 1;
    for (; t + 4 < L; t += 4) {
        vstep(stateBuf[0], stateBuf[1], t,     X0);
        vstep(stateBuf[1], stateBuf[0], t + 1, X1);
        vstep(stateBuf[0], stateBuf[1], t + 2, X2);
        vstep(stateBuf[1], stateBuf[0], t + 3, X3);
    }
    if (t     < L) vstep(stateBuf[0], stateBuf[1], t,     X0);
    if (t + 1 < L) vstep(stateBuf[1], stateBuf[0], t + 1, X1);
    if (t + 2 < L) vstep(stateBuf[0], stateBuf[1], t + 2, X2);
    if (t + 3 < L) vstep(stateBuf[1], stateBuf[0], t + 3, X3);

    __syncthreads();   // full drain: ws stores complete & visible
    const int pf = (L - 1) & 1;

    // Final argmax over state (first-occurrence: min index on ties).
    if (tid < NN) { redV[tid] = stateBuf[pf][SW(tid)]; redI[tid] = tid; }
    __syncthreads();
    #pragma unroll
    for (int off = 64; off >= 1; off >>= 1) {
        if (tid < off) {
            float va = redV[tid], vb = redV[tid + off];
            int   ia = redI[tid], ib = redI[tid + off];
            if (vb > va || (vb == va && ib < ia)) { redV[tid] = vb; redI[tid] = ib; }
        }
        __syncthreads();
    }

    // ---- Backtrack: wave 0, equality-ballot chase (byte-for-byte R3) ----
    if (tid < 64) {
        const int ln = tid;
        int jc = redI[0];
        if (ln == 0) tagBuf[L - 1] = jc;

        auto wrow = [&](int r) -> float2 {   // M row (clamped; clamped rows unused)
            r = (r < 0) ? 0 : r;
            return *(const float2*)(wsb + r * NN + 2 * ln);
        };
        auto xrow = [&](int r) -> float2 {   // logits row
            r = (r < 0) ? 0 : r;
            return *(const float2*)(lrow + r * NN + 2 * ln);
        };
        auto extract2 = [&](float2 v, int idx) -> float {  // v[idx], idx uniform
            int sel = idx >> 1;
            int wx = __builtin_amdgcn_readlane(__float_as_int(v.x), sel);
            int wy = __builtin_amdgcn_readlane(__float_as_int(v.y), sel);
            return __int_as_float((idx & 1) ? wy : wx);
        };

        float target;
        {
            float2 rT = wrow(L - 1);
            target = extract2(rT, jc);       // M[L-1][jc]
        }

        // chase step t: uses m = M[t-1] row, xr = x[t-1] row.
        // bp = first i with (m[i]+xr[i])+T[i][jc] == target (bitwise-exact
        // recompute of forward candidates -> exact first-occurrence argmax).
        auto chase = [&](float2 m, float2 xr, int tc) {
            float2 tp = *(const float2*)(tt + jc * TTS + 2 * ln);
            float cA = (m.x + xr.x) + tp.x;
            float cB = (m.y + xr.y) + tp.y;
            unsigned long long mA = __ballot(cA == target);
            unsigned long long mB = __ballot(cB == target);
            int iA = mA ? (2 * (__ffsll(mA) - 1))     : (1 << 30);
            int iB = mB ? (2 * (__ffsll(mB) - 1) + 1) : (1 << 30);
            int bp = (iA < iB) ? iA : iB;
            if (ln == 0) tagBuf[tc - 1] = bp;
            target = extract2(m, bp);        // M[t-1][bp] for the next step
            jc = bp;
        };

        // 8-deep prefetch ring, statically unrolled
        float2 m0 = wrow(L - 2), x0 = xrow(L - 2);
        float2 m1 = wrow(L - 3), x1 = xrow(L - 3);
        float2 m2 = wrow(L - 4), x2 = xrow(L - 4);
        float2 m3 = wrow(L - 5), x3 = xrow(L - 5);
        float2 m4 = wrow(L - 6), x4 = xrow(L - 6);
        float2 m5 = wrow(L - 7), x5 = xrow(L - 7);
        float2 m6 = wrow(L - 8), x6 = xrow(L - 8);
        float2 m7 = wrow(L - 9), x7 = xrow(L - 9);
        int tb = L - 1;
        while (tb >= 8) {
            chase(m0, x0, tb);     m0 = wrow(tb - 9);  x0 = xrow(tb - 9);
            chase(m1, x1, tb - 1); m1 = wrow(tb - 10); x1 = xrow(tb - 10);
            chase(m2, x2, tb - 2); m2 = wrow(tb - 11); x2 = xrow(tb - 11);
            chase(m3, x3, tb - 3); m3 = wrow(tb - 12); x3 = xrow(tb - 12);
            chase(m4, x4, tb - 4); m4 = wrow(tb - 13); x4 = xrow(tb - 13);
            chase(m5, x5, tb - 5); m5 = wrow(tb - 14); x5 = xrow(tb - 14);
            chase(m6, x6, tb - 6); m6 = wrow(tb - 15); x6 = xrow(tb - 15);
            chase(m7, x7, tb - 7); m7 = wrow(tb - 16); x7 = xrow(tb - 16);
            tb -= 8;
        }
        if (tb >= 1) chase(m0, x0, tb);
        if (tb >= 2) chase(m1, x1, tb - 1);
        if (tb >= 3) chase(m2, x2, tb - 2);
        if (tb >= 4) chase(m3, x3, tb - 3);
        if (tb >= 5) chase(m4, x4, tb - 4);
        if (tb >= 6) chase(m5, x5, tb - 5);
        if (tb >= 7) chase(m6, x6, tb - 6);
    }
    __syncthreads();

    // Coalesced output: tags for k < L, zeros for the masked tail.
    out[(size_t)b * TT + tid]       = (tid < L)       ? tagBuf[tid]       : 0;
    out[(size_t)b * TT + tid + 256] = (tid + 256 < L) ? tagBuf[tid + 256] : 0;
}

// ---------------- FALLBACK kernel: R5 (proven), used if ws too small --------
__global__ __launch_bounds__(FTHR, 1)
void crf_viterbi_fallback(const float* __restrict__ logits,
                          const float* __restrict__ trans,
                          const int* __restrict__ seqlen,
                          int* __restrict__ out) {
    __shared__ float stateBuf[2][FSROW];
    __shared__ float redV[NN];
    __shared__ int   redI[NN];
    __shared__ int   tagBuf[TT];
    __shared__ int   entryTag[MAXG];
    __shared__ unsigned char bp[TT][NN];
    __shared__ unsigned char hist[MAXG][BD][NN];

    const int tid = threadIdx.x;
    const int j   = tid >> 3;
    const int c   = tid & 7;
    const int i0  = c << 4;
    const int b   = blockIdx.x;
    const int L   = seqlen[b];

    float tr0[16], tr1[16];
    #pragma unroll
    for (int k = 0; k < 16; ++k) {
        tr0[k] = trans[(i0 + k) * NN + j];
        tr1[k] = trans[(i0 + k) * NN + j + 64];
    }

    const float* lrow = logits + (size_t)b * TT * NN;
    if (c < 2) {
        int jj = j + (c << 6);
        stateBuf[0][SWF(jj)] = lrow[jj];
    }
    __syncthreads();

    float xa0 = lrow[NN + j], xa1 = lrow[NN + j + 64];
    int p = 0;
    for (int t = 1; t < L; ++t) {
        int tn = (t + 1 < L) ? (t + 1) : (L - 1);
        const float* lp = lrow + tn * NN;
        float xb0 = lp[j];
        float xb1 = lp[j + 64];

        const float* st = stateBuf[p] + 20 * c;
        float4 a0 = *(const float4*)(st);
        float4 a1 = *(const float4*)(st + 4);
        float4 a2 = *(const float4*)(st + 8);
        float4 a3 = *(const float4*)(st + 12);

        float best0 = -__builtin_inff(), best1 = -__builtin_inff();
        int arg0 = 0, arg1 = 0;
        #define ELEM(S, K)                                                  \
        {                                                                   \
            float sc = (S) + tr0[K];                                        \
            bool g = sc > best0; best0 = g ? sc : best0; arg0 = g ? (K) : arg0; \
            float sd = (S) + tr1[K];                                        \
            bool h = sd > best1; best1 = h ? sd : best1; arg1 = h ? (K) : arg1; \
        }
        ELEM(a0.x, 0)  ELEM(a0.y, 1)  ELEM(a0.z, 2)  ELEM(a0.w, 3)
        ELEM(a1.x, 4)  ELEM(a1.y, 5)  ELEM(a1.z, 6)  ELEM(a1.w, 7)
        ELEM(a2.x, 8)  ELEM(a2.y, 9)  ELEM(a2.z, 10) ELEM(a2.w, 11)
        ELEM(a3.x, 12) ELEM(a3.y, 13) ELEM(a3.z, 14) ELEM(a3.w, 15)
        #undef ELEM

        float bv0 = best0, bv1 = best1;
        int   bi0 = i0 + arg0, bi1 = i0 + arg1;
        #define MERGE_STAGE(CTRL, LOWER)                                   \
        {                                                                  \
            float p0 = dpp_f<CTRL>(bv0); int q0 = dpp_i<CTRL>(bi0);        \
            float p1 = dpp_f<CTRL>(bv1); int q1 = dpp_i<CTRL>(bi1);        \
            bool lower = (LOWER);                                          \
            bool t0 = (p0 > bv0) || (p0 == bv0 && lower);                  \
            bool t1 = (p1 > bv1) || (p1 == bv1 && lower);                  \
            bv0 = t0 ? p0 : bv0; bi0 = t0 ? q0 : bi0;                      \
            bv1 = t1 ? p1 : bv1; bi1 = t1 ? q1 : bi1;                      \
        }
        MERGE_STAGE(DPP_XOR1, (c & 1) != 0)
        MERGE_STAGE(DPP_XOR2, (c & 2) != 0)
        MERGE_STAGE(DPP_MIR7, (c & 4) != 0)
        #undef MERGE_STAGE

        if (c < 2) {
            int   jj = j + (c << 6);
            float bv = c ? bv1 : bv0;
            int   bi = c ? bi1 : bi0;
            float xx = c ? xa1 : xa0;
            stateBuf[p ^ 1][SWF(jj)] = bv + xx;
            bp[t][jj] = (unsigned char)bi;
        }
        xa0 = xb0; xa1 = xb1;
        __syncthreads();
        p ^= 1;
    }

    if (tid < NN) { redV[tid] = stateBuf[p][SWF(tid)]; redI[tid] = tid; }
    __syncthreads();
    #pragma unroll
    for (int off = 64; off >= 1; off >>= 1) {
        if (tid < off) {
            float va = redV[tid], vb = redV[tid + off];
            int   ia = redI[tid], ib = redI[tid + off];
            if (vb > va || (vb == va && ib < ia)) { redV[tid] = vb; redI[tid] = ib; }
        }
        __syncthreads();
    }

    const int M = L - 1;
    const int G = (M + BD - 1) / BD;
    {
        int s  = tid & 127;
        int gA = tid >> 7;
        int gB = gA + 4;
        int thA = M - gA * BD, thB = M - gB * BD;
        int dA  = (gA < G) ? ((thA < BD) ? thA : BD) : 0;
        int dB  = (gB < G) ? ((thB < BD) ? thB : BD) : 0;
        int curA = s, curB = s;
        int maxd = (dA > dB) ? dA : dB;
        for (int d = 0; d < maxd; ++d) {
            if (d < dA) { curA = bp[thA - d][curA]; hist[gA][d][s] = (unsigned char)curA; }
            if (d < dB) { curB = bp[thB - d][curB]; hist[gB][d][s] = (unsigned char)curB; }
        }
    }
    __syncthreads();
    if (tid == 0) {
        int e = redI[0];
        tagBuf[L - 1] = e;
        for (int g = 0; g < G; ++g) {
            entryTag[g] = e;
            if (g + 1 < G) e = hist[g][BD - 1][e];
        }
    }
    __syncthreads();
    {
        int g = tid >> 6, d = tid & 63;
        if (g < MAXG && g < G) {
            int th  = M - g * BD;
            int dep = (th < BD) ? th : BD;
            if (d < dep) {
                int e = entryTag[g];
                tagBuf[th - 1 - d] = hist[g][d][e];
            }
        }
    }
    __syncthreads();
    out[(size_t)b * TT + tid] = (tid < L) ? tagBuf[tid] : 0;
}

extern "C" void kernel_launch(void* const* d_in, const int* in_sizes, int n_in,
                              void* d_out, int out_size, void* d_ws, size_t ws_size,
                              hipStream_t stream) {
    const float* logits = (const float*)d_in[0];
    const float* trans  = (const float*)d_in[1];
    const int*   seqlen = (const int*)d_in[2];
    int*         out    = (int*)d_out;
    const int B = in_sizes[2];  // 256
    const size_t need = (size_t)B * TT * NN * sizeof(float);  // 64 MiB
    if (ws_size >= need) {
        crf_viterbi_fast<<<B, NTHR, 0, stream>>>(logits, trans, seqlen, out,
                                                 (float*)d_ws);
    } else {
        crf_viterbi_fallback<<<B, FTHR, 0, stream>>>(logits, trans, seqlen, out);
    }
}

// Round 8
// 328.135 us; speedup vs baseline: 3.4963x; 1.2302x over previous
//
#include <hip/hip_runtime.h>

#define TT 512   // max sequence length T
#define NN 128   // number of tags N
#define NTHR 256 // FAST kernel: 4 waves = 1 wave per SIMD
#define FTHR 512 // fallback kernel thread count
#define SROW 160 // swizzled state row: 8 chunks x 20 floats (16 used + 4 pad)
#define SW(i) (20 * ((i) >> 4) + ((i) & 15))
#define TTS 130  // tt (T^T) row stride in floats: bank step 2, float2-aligned
#define BD  64   // (fallback kernel) backtrack chunk depth
#define MAXG 8   // (fallback kernel)

// Barrier WITHOUT vmcnt drain: LDS writes drained, global loads/stores stay
// in flight across the barrier.
#define STEP_BARRIER() asm volatile("s_waitcnt lgkmcnt(0)\n\ts_barrier" ::: "memory")

typedef float v2f __attribute__((ext_vector_type(2)));
__device__ __forceinline__ v2f vmax2(v2f a, v2f b) {
    v2f r; r.x = fmaxf(a.x, b.x); r.y = fmaxf(a.y, b.y); return r;
}

// DPP cross-lane (pure VALU, no LDS pipe)
template <int CTRL>
__device__ __forceinline__ int dpp_i(int x) {
    return __builtin_amdgcn_update_dpp(x, x, CTRL, 0xf, 0xf, true);
}
template <int CTRL>
__device__ __forceinline__ float dpp_f(float x) {
    union { float f; int i; } u; u.f = x;
    u.i = dpp_i<CTRL>(u.i);
    return u.f;
}
#define DPP_XOR1 0xB1   // quad_perm [1,0,3,2] : lane ^= 1
#define DPP_XOR2 0x4E   // quad_perm [2,3,0,1] : lane ^= 2
#define DPP_MIR7 0x141  // row_half_mirror (lane^=7): == ^4 after 1,2 (fallback)

// R17: R3 forward (proven best, untouched) + shortened chase chain.
// Chase chain cuts (exactness preserved):
//  1. ring stores s = m + x (refill-time add, bitwise == forward's S=M+x)
//     -> 1 add on-chain instead of 2.
//  2. single OR-ballot (cA==t || cB==t) -> first lane lf; per-lane preferred
//     (even-first) index/value via cndmask runs parallel to the SALU ffs.
//     min-lane-then-parity == global min index (lane l covers {2l,2l+1}).
//  3. bp and next target via 2 readlanes off the same lf (drops the second
//     ballot+ffs+select round of the old 2-parity scheme).
__global__ __launch_bounds__(NTHR, 1)
void crf_viterbi_fast(const float* __restrict__ logits,
                      const float* __restrict__ trans,
                      const int* __restrict__ seqlen,
                      int* __restrict__ out,
                      float* __restrict__ ws) {
    __shared__ float stateBuf[2][SROW];
    __shared__ float tt[NN * TTS];  // tt[j*TTS+i] = trans[i*NN+j]
    __shared__ float redV[NN];
    __shared__ int   redI[NN];
    __shared__ int   tagBuf[TT];

    const int tid = threadIdx.x;
    const int j   = tid >> 2;   // 0..63 (serves tags j and j+64)
    const int c   = tid & 3;    // i-chunk (32 i's each)
    const int i0  = c << 5;
    const int b   = blockIdx.x;
    const int L   = seqlen[b];  // in [1, TT]
    const int lm1 = L - 1;
    const int jx  = j + ((c & 1) << 6);

    const float* lrow = logits + (size_t)b * TT * NN;
    float* wsb = ws + (size_t)b * TT * NN;

    // 4-deep logits prefetch ring
    auto xl = [&](int r) -> float {
        r = (r < lm1) ? r : lm1;
        return lrow[r * NN + jx];
    };
    float X0 = xl(1), X1 = xl(2), X2 = xl(3), X3 = xl(4);

    // Transition chunks in registers, packed for v_pk_add_f32 / v_pk_max_f32
    v2f tr0[16], tr1[16];
    #pragma unroll
    for (int p = 0; p < 16; ++p) {
        tr0[p].x = trans[(i0 + 2 * p)     * NN + j];
        tr0[p].y = trans[(i0 + 2 * p + 1) * NN + j];
        tr1[p].x = trans[(i0 + 2 * p)     * NN + j + 64];
        tr1[p].y = trans[(i0 + 2 * p + 1) * NN + j + 64];
    }

    // Transposed copy for backtrack. Stride TTS=130: write bank step 2,
    // reads float2-aligned.
    for (int k = 0; k < (NN * NN) / NTHR; ++k) {
        int idx = k * NTHR + tid;
        tt[(idx & 127) * TTS + (idx >> 7)] = trans[idx];
    }

    if (c < 2) {   // t = 0 init: LDS state = x[0]; ws row 0 = 0 (M[0] := 0)
        stateBuf[0][SW(jx)] = lrow[jx];
        wsb[jx] = 0.0f;
    }
    __syncthreads();

    // 32-candidate packed add+max tree; value-only, order-invariant -> exact.
    #define REDUCE32(TR, OUT)                                                  \
    {                                                                          \
        v2f m0 = vmax2(sv0 + TR[0],  sv1 + TR[1]);                             \
        v2f m1 = vmax2(sv2 + TR[2],  sv3 + TR[3]);                             \
        v2f m2 = vmax2(sv4 + TR[4],  sv5 + TR[5]);                             \
        v2f m3 = vmax2(sv6 + TR[6],  sv7 + TR[7]);                             \
        v2f m4 = vmax2(sv8 + TR[8],  sv9 + TR[9]);                             \
        v2f m5 = vmax2(sv10 + TR[10], sv11 + TR[11]);                          \
        v2f m6 = vmax2(sv12 + TR[12], sv13 + TR[13]);                          \
        v2f m7 = vmax2(sv14 + TR[14], sv15 + TR[15]);                          \
        m0 = vmax2(m0, m1); m2 = vmax2(m2, m3);                                \
        m4 = vmax2(m4, m5); m6 = vmax2(m6, m7);                                \
        m0 = vmax2(m0, m2); m4 = vmax2(m4, m6);                                \
        m0 = vmax2(m0, m4);                                                    \
        OUT = fmaxf(m0.x, m0.y);                                               \
    }

    auto vstep = [&](const float* st, float* dst, int t, float& xslot) {
        float xa_use = xslot;          // x[t], loaded 4 steps ago
        int tn = t + 4;                // refill ring slot with x[t+4]
        tn = (tn < lm1) ? tn : lm1;
        xslot = lrow[tn * NN + jx];

        // two 20-float chunks (chunks 2c and 2c+1 of the swizzled row)
        const float* sp = st + 40 * c;
        float4 a0 = *(const float4*)(sp);
        float4 a1 = *(const float4*)(sp + 4);
        float4 a2 = *(const float4*)(sp + 8);
        float4 a3 = *(const float4*)(sp + 12);
        float4 a4 = *(const float4*)(sp + 20);
        float4 a5 = *(const float4*)(sp + 24);
        float4 a6 = *(const float4*)(sp + 28);
        float4 a7 = *(const float4*)(sp + 32);

        v2f sv0  = {a0.x, a0.y}, sv1  = {a0.z, a0.w};
        v2f sv2  = {a1.x, a1.y}, sv3  = {a1.z, a1.w};
        v2f sv4  = {a2.x, a2.y}, sv5  = {a2.z, a2.w};
        v2f sv6  = {a3.x, a3.y}, sv7  = {a3.z, a3.w};
        v2f sv8  = {a4.x, a4.y}, sv9  = {a4.z, a4.w};
        v2f sv10 = {a5.x, a5.y}, sv11 = {a5.z, a5.w};
        v2f sv12 = {a6.x, a6.y}, sv13 = {a6.z, a6.w};
        v2f sv14 = {a7.x, a7.y}, sv15 = {a7.z, a7.w};

        float bv0, bv1;
        REDUCE32(tr0, bv0)
        REDUCE32(tr1, bv1)

        // value-only quad merge (c = 0..3)
        bv0 = fmaxf(bv0, dpp_f<DPP_XOR1>(bv0)); bv1 = fmaxf(bv1, dpp_f<DPP_XOR1>(bv1));
        bv0 = fmaxf(bv0, dpp_f<DPP_XOR2>(bv0)); bv1 = fmaxf(bv1, dpp_f<DPP_XOR2>(bv1));

        if (c < 2) {
            float bv = c ? bv1 : bv0;
            dst[SW(jx)] = bv + xa_use; // next step's state S[t]
            wsb[t * NN + jx] = bv;     // pre-logit max M[t] (for backtrack)
        }
        STEP_BARRIER();   // lgkm-only: global loads/stores stay in flight
    };
    #undef REDUCE32

    int t = 1;
    for (; t + 4 < L; t += 4) {
        vstep(stateBuf[0], stateBuf[1], t,     X0);
        vstep(stateBuf[1], stateBuf[0], t + 1, X1);
        vstep(stateBuf[0], stateBuf[1], t + 2, X2);
        vstep(stateBuf[1], stateBuf[0], t + 3, X3);
    }
    if (t     < L) vstep(stateBuf[0], stateBuf[1], t,     X0);
    if (t + 1 < L) vstep(stateBuf[1], stateBuf[0], t + 1, X1);
    if (t + 2 < L) vstep(stateBuf[0], stateBuf[1], t + 2, X2);
    if (t + 3 < L) vstep(stateBuf[1], stateBuf[0], t + 3, X3);

    __syncthreads();   // full drain: ws stores complete & visible
    const int pf = (L - 1) & 1;

    // Final argmax over state (first-occurrence: min index on ties).
    if (tid < NN) { redV[tid] = stateBuf[pf][SW(tid)]; redI[tid] = tid; }
    __syncthreads();
    #pragma unroll
    for (int off = 64; off >= 1; off >>= 1) {
        if (tid < off) {
            float va = redV[tid], vb = redV[tid + off];
            int   ia = redI[tid], ib = redI[tid + off];
            if (vb > va || (vb == va && ib < ia)) { redV[tid] = vb; redI[tid] = ib; }
        }
        __syncthreads();
    }

    // ---- Backtrack: wave 0, shortened equality-ballot chase ----
    if (tid < 64) {
        const int lane = tid;
        int jc = redI[0];
        if (lane == 0) tagBuf[L - 1] = jc;

        auto wrow = [&](int r) -> float2 {   // M row (clamped; clamped rows unused)
            r = (r < 0) ? 0 : r;
            return *(const float2*)(wsb + r * NN + 2 * lane);
        };
        auto xrow = [&](int r) -> float2 {   // logits row
            r = (r < 0) ? 0 : r;
            return *(const float2*)(lrow + r * NN + 2 * lane);
        };
        auto extract2 = [&](float2 v, int idx) -> float {  // v[idx], idx uniform
            int sel = idx >> 1;
            int wx = __builtin_amdgcn_readlane(__float_as_int(v.x), sel);
            int wy = __builtin_amdgcn_readlane(__float_as_int(v.y), sel);
            return __int_as_float((idx & 1) ? wy : wx);
        };

        float target;
        {
            float2 rT = wrow(L - 1);
            target = extract2(rT, jc);       // M[L-1][jc]
        }

        // chase step t: m = M[t-1] row, s = m + x[t-1] (refill-time add,
        // bitwise == forward's state S[t-1]). bp = first i with
        // s[i]+T[i][jc] == target. Single OR-ballot; lane lf = first matching
        // lane; even-first within lane -> global min index (lane l covers
        // {2l, 2l+1}) -> exact first-occurrence argmax, same as before.
        auto chase = [&](float2 m, float2 s, int tc) {
            float2 tp = *(const float2*)(tt + jc * TTS + 2 * lane);
            float cA = s.x + tp.x;
            float cB = s.y + tp.y;
            bool eA = (cA == target);
            bool eB = (cB == target);
            unsigned long long mm = __ballot(eA || eB);
            int lf = __ffsll((long long)mm) - 1;        // first matching lane
            int   idxl = 2 * lane + (eA ? 0 : 1);       // preferred idx (even first)
            float vall = eA ? m.x : m.y;                // matching M value
            int bp = __builtin_amdgcn_readlane(idxl, lf);
            target = __int_as_float(
                __builtin_amdgcn_readlane(__float_as_int(vall), lf));
            if (lane == 0) tagBuf[tc - 1] = bp;
            jc = bp;
        };

        // 8-deep prefetch ring: m (M row) + s = m + x (precomputed off-chain)
        float2 m0, s0, m1, s1, m2, s2, m3, s3, m4, s4, m5, s5, m6, s6, m7, s7;
        #define RING_FILL(MM, SS, R)                                           \
        { MM = wrow(R); float2 xr_ = xrow(R);                                  \
          SS.x = MM.x + xr_.x; SS.y = MM.y + xr_.y; }
        RING_FILL(m0, s0, L - 2)
        RING_FILL(m1, s1, L - 3)
        RING_FILL(m2, s2, L - 4)
        RING_FILL(m3, s3, L - 5)
        RING_FILL(m4, s4, L - 6)
        RING_FILL(m5, s5, L - 7)
        RING_FILL(m6, s6, L - 8)
        RING_FILL(m7, s7, L - 9)
        int tb = L - 1;
        while (tb >= 8) {
            chase(m0, s0, tb);     RING_FILL(m0, s0, tb - 9)
            chase(m1, s1, tb - 1); RING_FILL(m1, s1, tb - 10)
            chase(m2, s2, tb - 2); RING_FILL(m2, s2, tb - 11)
            chase(m3, s3, tb - 3); RING_FILL(m3, s3, tb - 12)
            chase(m4, s4, tb - 4); RING_FILL(m4, s4, tb - 13)
            chase(m5, s5, tb - 5); RING_FILL(m5, s5, tb - 14)
            chase(m6, s6, tb - 6); RING_FILL(m6, s6, tb - 15)
            chase(m7, s7, tb - 7); RING_FILL(m7, s7, tb - 16)
            tb -= 8;
        }
        if (tb >= 1) chase(m0, s0, tb);
        if (tb >= 2) chase(m1, s1, tb - 1);
        if (tb >= 3) chase(m2, s2, tb - 2);
        if (tb >= 4) chase(m3, s3, tb - 3);
        if (tb >= 5) chase(m4, s4, tb - 4);
        if (tb >= 6) chase(m5, s5, tb - 5);
        if (tb >= 7) chase(m6, s6, tb - 6);
        #undef RING_FILL
    }
    __syncthreads();

    // Coalesced output: tags for k < L, zeros for the masked tail.
    out[(size_t)b * TT + tid]       = (tid < L)       ? tagBuf[tid]       : 0;
    out[(size_t)b * TT + tid + 256] = (tid + 256 < L) ? tagBuf[tid + 256] : 0;
}

// ---------------- FALLBACK kernel: R5 (proven), used if ws too small --------
__global__ __launch_bounds__(FTHR, 1)
void crf_viterbi_fallback(const float* __restrict__ logits,
                          const float* __restrict__ trans,
                          const int* __restrict__ seqlen,
                          int* __restrict__ out) {
    __shared__ float stateBuf[2][SROW];
    __shared__ float redV[NN];
    __shared__ int   redI[NN];
    __shared__ int   tagBuf[TT];
    __shared__ int   entryTag[MAXG];
    __shared__ unsigned char bp[TT][NN];
    __shared__ unsigned char hist[MAXG][BD][NN];

    const int tid = threadIdx.x;
    const int j   = tid >> 3;
    const int c   = tid & 7;
    const int i0  = c << 4;
    const int b   = blockIdx.x;
    const int L   = seqlen[b];

    float tr0[16], tr1[16];
    #pragma unroll
    for (int k = 0; k < 16; ++k) {
        tr0[k] = trans[(i0 + k) * NN + j];
        tr1[k] = trans[(i0 + k) * NN + j + 64];
    }

    const float* lrow = logits + (size_t)b * TT * NN;
    if (c < 2) {
        int jj = j + (c << 6);
        stateBuf[0][SW(jj)] = lrow[jj];
    }
    __syncthreads();

    float xa0 = lrow[NN + j], xa1 = lrow[NN + j + 64];
    int p = 0;
    for (int t = 1; t < L; ++t) {
        int tn = (t + 1 < L) ? (t + 1) : (L - 1);
        const float* lp = lrow + tn * NN;
        float xb0 = lp[j];
        float xb1 = lp[j + 64];

        const float* st = stateBuf[p] + 20 * c;
        float4 a0 = *(const float4*)(st);
        float4 a1 = *(const float4*)(st + 4);
        float4 a2 = *(const float4*)(st + 8);
        float4 a3 = *(const float4*)(st + 12);

        float best0 = -__builtin_inff(), best1 = -__builtin_inff();
        int arg0 = 0, arg1 = 0;
        #define ELEM(S, K)                                                  \
        {                                                                   \
            float sc = (S) + tr0[K];                                        \
            bool g = sc > best0; best0 = g ? sc : best0; arg0 = g ? (K) : arg0; \
            float sd = (S) + tr1[K];                                        \
            bool h = sd > best1; best1 = h ? sd : best1; arg1 = h ? (K) : arg1; \
        }
        ELEM(a0.x, 0)  ELEM(a0.y, 1)  ELEM(a0.z, 2)  ELEM(a0.w, 3)
        ELEM(a1.x, 4)  ELEM(a1.y, 5)  ELEM(a1.z, 6)  ELEM(a1.w, 7)
        ELEM(a2.x, 8)  ELEM(a2.y, 9)  ELEM(a2.z, 10) ELEM(a2.w, 11)
        ELEM(a3.x, 12) ELEM(a3.y, 13) ELEM(a3.z, 14) ELEM(a3.w, 15)
        #undef ELEM

        float bv0 = best0, bv1 = best1;
        int   bi0 = i0 + arg0, bi1 = i0 + arg1;
        #define MERGE_STAGE(CTRL, LOWER)                                   \
        {                                                                  \
            float p0 = dpp_f<CTRL>(bv0); int q0 = dpp_i<CTRL>(bi0);        \
            float p1 = dpp_f<CTRL>(bv1); int q1 = dpp_i<CTRL>(bi1);        \
            bool lower = (LOWER);                                          \
            bool t0 = (p0 > bv0) || (p0 == bv0 && lower);                  \
            bool t1 = (p1 > bv1) || (p1 == bv1 && lower);                  \
            bv0 = t0 ? p0 : bv0; bi0 = t0 ? q0 : bi0;                      \
            bv1 = t1 ? p1 : bv1; bi1 = t1 ? q1 : bi1;                      \
        }
        MERGE_STAGE(DPP_XOR1, (c & 1) != 0)
        MERGE_STAGE(DPP_XOR2, (c & 2) != 0)
        MERGE_STAGE(DPP_MIR7, (c & 4) != 0)
        #undef MERGE_STAGE

        if (c < 2) {
            int   jj = j + (c << 6);
            float bv = c ? bv1 : bv0;
            int   bi = c ? bi1 : bi0;
            float xx = c ? xa1 : xa0;
            stateBuf[p ^ 1][SW(jj)] = bv + xx;
            bp[t][jj] = (unsigned char)bi;
        }
        xa0 = xb0; xa1 = xb1;
        __syncthreads();
        p ^= 1;
    }

    if (tid < NN) { redV[tid] = stateBuf[p][SW(tid)]; redI[tid] = tid; }
    __syncthreads();
    #pragma unroll
    for (int off = 64; off >= 1; off >>= 1) {
        if (tid < off) {
            float va = redV[tid], vb = redV[tid + off];
            int   ia = redI[tid], ib = redI[tid + off];
            if (vb > va || (vb == va && ib < ia)) { redV[tid] = vb; redI[tid] = ib; }
        }
        __syncthreads();
    }

    const int M = L - 1;
    const int G = (M + BD - 1) / BD;
    {
        int s  = tid & 127;
        int gA = tid >> 7;
        int gB = gA + 4;
        int thA = M - gA * BD, thB = M - gB * BD;
        int dA  = (gA < G) ? ((thA < BD) ? thA : BD) : 0;
        int dB  = (gB < G) ? ((thB < BD) ? thB : BD) : 0;
        int curA = s, curB = s;
        int maxd = (dA > dB) ? dA : dB;
        for (int d = 0; d < maxd; ++d) {
            if (d < dA) { curA = bp[thA - d][curA]; hist[gA][d][s] = (unsigned char)curA; }
            if (d < dB) { curB = bp[thB - d][curB]; hist[gB][d][s] = (unsigned char)curB; }
        }
    }
    __syncthreads();
    if (tid == 0) {
        int e = redI[0];
        tagBuf[L - 1] = e;
        for (int g = 0; g < G; ++g) {
            entryTag[g] = e;
            if (g + 1 < G) e = hist[g][BD - 1][e];
        }
    }
    __syncthreads();
    {
        int g = tid >> 6, d = tid & 63;
        if (g < MAXG && g < G) {
            int th  = M - g * BD;
            int dep = (th < BD) ? th : BD;
            if (d < dep) {
                int e = entryTag[g];
                tagBuf[th - 1 - d] = hist[g][d][e];
            }
        }
    }
    __syncthreads();
    out[(size_t)b * TT + tid] = (tid < L) ? tagBuf[tid] : 0;
}

extern "C" void kernel_launch(void* const* d_in, const int* in_sizes, int n_in,
                              void* d_out, int out_size, void* d_ws, size_t ws_size,
                              hipStream_t stream) {
    const float* logits = (const float*)d_in[0];
    const float* trans  = (const float*)d_in[1];
    const int*   seqlen = (const int*)d_in[2];
    int*         out    = (int*)d_out;
    const int B = in_sizes[2];  // 256
    const size_t need = (size_t)B * TT * NN * sizeof(float);  // 64 MiB
    if (ws_size >= need) {
        crf_viterbi_fast<<<B, NTHR, 0, stream>>>(logits, trans, seqlen, out,
                                                 (float*)d_ws);
    } else {
        crf_viterbi_fallback<<<B, FTHR, 0, stream>>>(logits, trans, seqlen, out);
    }
}